// Round 10
// baseline (82.220 us; speedup 1.0000x reference)
//
#include <hip/hip_runtime.h>
#include <cmath>

#define HID 1024
#define OUTN 512
#define VOCABN 1024
#define MSIZE 262144
#define MDIM 128

// ws float layout
#define WS_HB 0     // [1024] hidden_bar
#define WS_H  1024  // [1024] h

__device__ __forceinline__ float wred(float v) {
#pragma unroll
    for (int m = 32; m; m >>= 1) v += __shfl_xor(v, m, 64);
    return v;
}

// wave-cooperative dot over n4 float4s (result in all lanes)
__device__ __forceinline__ float dot4(const float4* __restrict__ a,
                                      const float4* __restrict__ b,
                                      int n4, int lane) {
    float acc = 0.f;
    for (int k = lane; k < n4; k += 64) {
        float4 x = a[k], y = b[k];
        acc = fmaf(x.x, y.x, fmaf(x.y, y.y, fmaf(x.z, y.z, fmaf(x.w, y.w, acc))));
    }
    return wred(acc);
}

__device__ __forceinline__ float4 blend4(float aw0, float aw1, float4 push, float4 pop) {
    float4 r;
    r.x = fmaf(aw0, push.x, aw1 * pop.x);
    r.y = fmaf(aw0, push.y, aw1 * pop.y);
    r.z = fmaf(aw0, push.z, aw1 * pop.z);
    r.w = fmaf(aw0, push.w, aw1 * pop.w);
    return r;
}

// K1: hidden_bar[row] = W_sh[row,:]·stack[0,:] + b_sh[row] + hidden0[row]
__global__ __launch_bounds__(256) void k_hb(
    const float* __restrict__ stack, const float* __restrict__ hidden0,
    const float* __restrict__ W_sh, const float* __restrict__ b_sh,
    float* __restrict__ ws) {
    const int lane = threadIdx.x & 63;
    const int row = blockIdx.x * 4 + (threadIdx.x >> 6);
    if (row >= HID) return;
    const float hb = dot4((const float4*)(W_sh + row * MDIM), (const float4*)stack,
                          MDIM / 4, lane);
    if (lane == 0) ws[WS_HB + row] = hb + b_sh[row] + hidden0[row];
}

// K2: h[R] = tanh(W_ih[R]·input + W_hh[R]·hb + b_ih[R] + b_hh[R])
__global__ __launch_bounds__(256) void k_h3(
    const float* __restrict__ input, const float* __restrict__ W_ih,
    const float* __restrict__ W_hh, const float* __restrict__ b_ih,
    const float* __restrict__ b_hh, float* __restrict__ ws,
    float* __restrict__ d_out) {
    const int lane = threadIdx.x & 63;
    const int R = blockIdx.x * 4 + (threadIdx.x >> 6);
    if (R >= HID) return;
    const float4* wi  = (const float4*)(W_ih + R * VOCABN);
    const float4* wh  = (const float4*)(W_hh + R * HID);
    const float4* in4 = (const float4*)input;
    const float4* hb4 = (const float4*)(ws + WS_HB);
    float acc = 0.f;
    for (int k = lane; k < VOCABN / 4; k += 64) {
        float4 a = wi[k], b = in4[k];
        acc = fmaf(a.x, b.x, fmaf(a.y, b.y, fmaf(a.z, b.z, fmaf(a.w, b.w, acc))));
        float4 c = wh[k], d = hb4[k];
        acc = fmaf(c.x, d.x, fmaf(c.y, d.y, fmaf(c.z, d.z, fmaf(c.w, d.w, acc))));
    }
    acc = wred(acc);
    if (lane == 0) {
        const float h = tanhf(acc + b_ih[R] + b_hh[R]);
        ws[WS_H + R] = h;
        d_out[OUTN + R] = h;
    }
}

// K3: heads + blend merged, no cross-block sync, R9 blend structure preserved.
// Every block: waves 0/1 compute the two action logits redundantly -> LDS.
// Block 0: computes new_elt privately (LDS) and blends ONLY float4s [0,32).
// Blocks 1..2047: branchless grid-stride blend over [32, total4);
// blocks 1..512 additionally compute one W_y output row post-blend.
__global__ __launch_bounds__(256, 8) void k_stack3(
    const float* __restrict__ stack, const float* __restrict__ W_y,
    const float* __restrict__ b_y, const float* __restrict__ W_n,
    const float* __restrict__ b_n, const float* __restrict__ W_a,
    const float* __restrict__ b_a, const float* __restrict__ ws,
    float* __restrict__ d_out) {
    __shared__ float s_logit[2];
    __shared__ __align__(16) float s_ne[MDIM];
    const int b    = blockIdx.x;
    const int t    = threadIdx.x;
    const int lane = t & 63;
    const int wave = t >> 6;   // 0..3
    const float4* h4 = (const float4*)(ws + WS_H);

    // action logits (waves 0 and 1, redundant per block)
    if (wave < 2) {
        const float l = dot4((const float4*)(W_a + wave * HID), h4, HID / 4, lane);
        if (lane == 0) s_logit[wave] = l + b_a[wave];
    }

    // block 0: new_elt (128 rows), 4 waves x 32 rows, 4-row batches
    if (b == 0) {
        for (int g = 0; g < 32; g += 4) {
            const int m = wave * 32 + g;
            const float4* r0 = (const float4*)(W_n + (m + 0) * HID);
            const float4* r1 = (const float4*)(W_n + (m + 1) * HID);
            const float4* r2 = (const float4*)(W_n + (m + 2) * HID);
            const float4* r3 = (const float4*)(W_n + (m + 3) * HID);
            float a0 = 0.f, a1 = 0.f, a2 = 0.f, a3 = 0.f;
            for (int k = lane; k < HID / 4; k += 64) {
                const float4 hv = h4[k];
                const float4 w0 = r0[k], w1 = r1[k], w2 = r2[k], w3 = r3[k];
                a0 = fmaf(w0.x, hv.x, fmaf(w0.y, hv.y, fmaf(w0.z, hv.z, fmaf(w0.w, hv.w, a0))));
                a1 = fmaf(w1.x, hv.x, fmaf(w1.y, hv.y, fmaf(w1.z, hv.z, fmaf(w1.w, hv.w, a1))));
                a2 = fmaf(w2.x, hv.x, fmaf(w2.y, hv.y, fmaf(w2.z, hv.z, fmaf(w2.w, hv.w, a2))));
                a3 = fmaf(w3.x, hv.x, fmaf(w3.y, hv.y, fmaf(w3.z, hv.z, fmaf(w3.w, hv.w, a3))));
            }
            a0 = wred(a0); a1 = wred(a1); a2 = wred(a2); a3 = wred(a3);
            if (lane == 0) {
                s_ne[m + 0] = 1.f / (1.f + expf(-(a0 + b_n[m + 0])));
                s_ne[m + 1] = 1.f / (1.f + expf(-(a1 + b_n[m + 1])));
                s_ne[m + 2] = 1.f / (1.f + expf(-(a2 + b_n[m + 2])));
                s_ne[m + 3] = 1.f / (1.f + expf(-(a3 + b_n[m + 3])));
            }
        }
    }
    __syncthreads();

    const float l0 = s_logit[0], l1 = s_logit[1];
    const float mx = fmaxf(l0, l1);
    const float e0 = expf(l0 - mx), e1 = expf(l1 - mx);
    const float inv = 1.f / (e0 + e1);
    const float aw0 = e0 * inv, aw1 = e1 * inv;

    const float4* s4 = (const float4*)stack;
    float4* o4 = (float4*)(d_out + OUTN + HID);
    const int total4 = MSIZE * (MDIM / 4);  // 8,388,608

    if (b == 0) {
        // stack row 0 only: push = new_elt, pop = stack row 1
        if (t < 32) {
            const float4* ne4 = (const float4*)s_ne;
            o4[t] = blend4(aw0, aw1, ne4[t], s4[t + 32]);
        }
        return;
    }

    // blocks 1..2047: e >= 32 so push = s4[e-32] always; only pop needs the
    // last-row select. Branchless, unrolled, R9 pattern.
    const int stride = (gridDim.x - 1) * blockDim.x;  // 524,032
    int e = 32 + (b - 1) * 256 + t;
#pragma unroll 4
    for (; e < total4; e += stride) {
        const float4 push = s4[e - 32];
        const int row = e >> 5;
        const int pe = (row == MSIZE - 1) ? (e - 32) : (e + 32);
        float4 pop = s4[pe];
        if (row == MSIZE - 1) pop = make_float4(0.f, 0.f, 0.f, 0.f);
        o4[e] = blend4(aw0, aw1, push, pop);
    }

    // output head tail: blocks 1..512, wave 0, one row each (hidden by blend)
    if (b <= OUTN && wave == 0) {
        const int r = b - 1;
        const float a = dot4((const float4*)(W_y + r * HID), h4, HID / 4, lane);
        if (lane == 0) d_out[r] = 1.f / (1.f + expf(-(a + b_y[r])));
    }
}

extern "C" void kernel_launch(void* const* d_in, const int* in_sizes, int n_in,
                              void* d_out, int out_size, void* d_ws, size_t ws_size,
                              hipStream_t stream) {
    const float* input   = (const float*)d_in[0];
    const float* hidden0 = (const float*)d_in[1];
    const float* stack   = (const float*)d_in[2];
    const float* W_ih    = (const float*)d_in[3];
    const float* W_hh    = (const float*)d_in[4];
    const float* b_ih    = (const float*)d_in[5];
    const float* b_hh    = (const float*)d_in[6];
    const float* W_y     = (const float*)d_in[7];
    const float* b_y     = (const float*)d_in[8];
    const float* W_n     = (const float*)d_in[9];
    const float* b_n     = (const float*)d_in[10];
    const float* W_a     = (const float*)d_in[11];
    const float* b_a     = (const float*)d_in[12];
    const float* W_sh    = (const float*)d_in[13];
    const float* b_sh    = (const float*)d_in[14];
    float* out = (float*)d_out;
    float* ws  = (float*)d_ws;

    k_hb<<<256, 256, 0, stream>>>(stack, hidden0, W_sh, b_sh, ws);
    k_h3<<<256, 256, 0, stream>>>(input, W_ih, W_hh, b_ih, b_hh, ws, out);
    k_stack3<<<2048, 256, 0, stream>>>(stack, W_y, b_y, W_n, b_n, W_a, b_a, ws, out);
}

// Round 11
// 68.012 us; speedup vs baseline: 1.2089x; 1.2089x over previous
//
#include <hip/hip_runtime.h>
#include <cmath>

#define HID 1024
#define OUTN 512
#define VOCABN 1024
#define MSIZE 262144
#define MDIM 128

// workspace layout (floats)
#define WS_TIH 0      // [1024] W_ih@input + b_ih
#define WS_HB  1024   // [1024] hidden_bar
#define WS_H   2048   // [1024] h
#define WS_AW  3072   // [2]    softmax action weights
#define WS_NE  3076   // [128]  new_elt (16B aligned)

__device__ __forceinline__ float wred(float v) {
#pragma unroll
    for (int m = 32; m; m >>= 1) v += __shfl_xor(v, m, 64);
    return v;
}

// wave-cooperative dot over n4 float4s (result in all lanes)
__device__ __forceinline__ float dot4(const float4* __restrict__ a,
                                      const float4* __restrict__ b,
                                      int n4, int lane) {
    float acc = 0.f;
    for (int k = lane; k < n4; k += 64) {
        float4 x = a[k], y = b[k];
        acc = fmaf(x.x, y.x, fmaf(x.y, y.y, fmaf(x.z, y.z, fmaf(x.w, y.w, acc))));
    }
    return wred(acc);
}

__device__ __forceinline__ float4 blend4(float aw0, float aw1, float4 push, float4 pop) {
    float4 r;
    r.x = fmaf(aw0, push.x, aw1 * pop.x);
    r.y = fmaf(aw0, push.y, aw1 * pop.y);
    r.z = fmaf(aw0, push.z, aw1 * pop.z);
    r.w = fmaf(aw0, push.w, aw1 * pop.w);
    return r;
}

// Kernel A: t_ih[row] = W_ih[row,:]·input + b_ih[row]
//           hidden_bar[row] = W_sh[row,:]·stack[0,:] + b_sh[row] + hidden0[row]
__global__ void k_pre(const float* __restrict__ input, const float* __restrict__ hidden0,
                      const float* __restrict__ stack, const float* __restrict__ W_ih,
                      const float* __restrict__ b_ih, const float* __restrict__ W_sh,
                      const float* __restrict__ b_sh, float* __restrict__ ws) {
    const int lane = threadIdx.x & 63;
    const int row = blockIdx.x * (blockDim.x >> 6) + (threadIdx.x >> 6);
    if (row >= HID) return;
    float t  = dot4((const float4*)(W_ih + row * VOCABN), (const float4*)input, VOCABN / 4, lane);
    float hb = dot4((const float4*)(W_sh + row * MDIM), (const float4*)stack, MDIM / 4, lane);
    if (lane == 0) {
        ws[WS_TIH + row] = t + b_ih[row];
        ws[WS_HB + row]  = hb + b_sh[row] + hidden0[row];
    }
}

// Kernel B: h[row] = tanh(t_ih[row] + W_hh[row,:]·hidden_bar + b_hh[row])
__global__ void k_h(const float* __restrict__ W_hh, const float* __restrict__ b_hh,
                    float* __restrict__ ws, float* __restrict__ d_out) {
    const int lane = threadIdx.x & 63;
    const int row = blockIdx.x * (blockDim.x >> 6) + (threadIdx.x >> 6);
    if (row >= HID) return;
    float a = dot4((const float4*)(W_hh + row * HID), (const float4*)(ws + WS_HB), HID / 4, lane);
    if (lane == 0) {
        float h = tanhf(ws[WS_TIH + row] + a + b_hh[row]);
        ws[WS_H + row] = h;
        d_out[OUTN + row] = h;
    }
}

// Kernel C: output (512), new_elt (128), action softmax (1 wave)
__global__ void k_heads(const float* __restrict__ W_y, const float* __restrict__ b_y,
                        const float* __restrict__ W_n, const float* __restrict__ b_n,
                        const float* __restrict__ W_a, const float* __restrict__ b_a,
                        float* __restrict__ ws, float* __restrict__ d_out) {
    const int lane = threadIdx.x & 63;
    const int row = blockIdx.x * (blockDim.x >> 6) + (threadIdx.x >> 6);
    const float4* h4 = (const float4*)(ws + WS_H);
    if (row < OUTN) {
        float a = dot4((const float4*)(W_y + row * HID), h4, HID / 4, lane);
        if (lane == 0) d_out[row] = 1.f / (1.f + expf(-(a + b_y[row])));
    } else if (row < OUTN + MDIM) {
        const int m = row - OUTN;
        float a = dot4((const float4*)(W_n + m * HID), h4, HID / 4, lane);
        if (lane == 0) ws[WS_NE + m] = 1.f / (1.f + expf(-(a + b_n[m])));
    } else if (row == OUTN + MDIM) {
        float l0 = dot4((const float4*)(W_a), h4, HID / 4, lane);
        float l1 = dot4((const float4*)(W_a + HID), h4, HID / 4, lane);
        if (lane == 0) {
            l0 += b_a[0];
            l1 += b_a[1];
            const float mx = fmaxf(l0, l1);
            const float e0 = expf(l0 - mx), e1 = expf(l1 - mx);
            const float s = e0 + e1;
            ws[WS_AW]     = e0 / s;
            ws[WS_AW + 1] = e1 / s;
        }
    }
}

// Kernel D: sliding-window blend. Each wave owns a contiguous 1024-float4
// segment. out[e] = aw0*s[e-32] + aw1*s[e+32]; a wave's 64 lanes cover 64
// consecutive float4s, so iteration i's pop chunk s[A+32+lane] is iteration
// i+1's push chunk -> keep it in a register. 1 load + 1 store per iter
// (copy-equivalent instruction stream), no shuffles.
__global__ __launch_bounds__(256, 8) void k_stack(
    const float* __restrict__ stack, const float* __restrict__ ws,
    float* __restrict__ out_stack) {
    const float aw0 = ws[WS_AW];
    const float aw1 = ws[WS_AW + 1];
    const float4* s4  = (const float4*)stack;
    const float4* ne4 = (const float4*)(ws + WS_NE);
    float4* o4 = (float4*)out_stack;
    const int total4 = MSIZE * (MDIM / 4);              // 8,388,608
    const int lane = threadIdx.x & 63;
    const int wid  = blockIdx.x * 4 + (threadIdx.x >> 6);  // 0..8191
    const long base = (long)wid * 1024;

    float4 prev;
    if (wid == 0) prev = (lane < 32) ? ne4[lane] : s4[lane - 32];
    else          prev = s4[base - 32 + lane];

#pragma unroll 4
    for (int i = 0; i < 16; ++i) {
        const long A = base + i * 64;
        const long nidx = A + 32 + lane;
        float4 next = make_float4(0.f, 0.f, 0.f, 0.f);
        if (nidx < total4) next = s4[nidx];
        o4[A + lane] = blend4(aw0, aw1, prev, next);
        prev = next;
    }
}

extern "C" void kernel_launch(void* const* d_in, const int* in_sizes, int n_in,
                              void* d_out, int out_size, void* d_ws, size_t ws_size,
                              hipStream_t stream) {
    const float* input   = (const float*)d_in[0];
    const float* hidden0 = (const float*)d_in[1];
    const float* stack   = (const float*)d_in[2];
    const float* W_ih    = (const float*)d_in[3];
    const float* W_hh    = (const float*)d_in[4];
    const float* b_ih    = (const float*)d_in[5];
    const float* b_hh    = (const float*)d_in[6];
    const float* W_y     = (const float*)d_in[7];
    const float* b_y     = (const float*)d_in[8];
    const float* W_n     = (const float*)d_in[9];
    const float* b_n     = (const float*)d_in[10];
    const float* W_a     = (const float*)d_in[11];
    const float* b_a     = (const float*)d_in[12];
    const float* W_sh    = (const float*)d_in[13];
    const float* b_sh    = (const float*)d_in[14];
    float* out = (float*)d_out;
    float* ws  = (float*)d_ws;

    // A: 1024 rows, 4 waves/block -> 256 blocks
    k_pre<<<256, 256, 0, stream>>>(input, hidden0, stack, W_ih, b_ih, W_sh, b_sh, ws);
    // B: 1024 rows
    k_h<<<256, 256, 0, stream>>>(W_hh, b_hh, ws, out);
    // C: 641 rows
    k_heads<<<161, 256, 0, stream>>>(W_y, b_y, W_n, b_n, W_a, b_a, ws, out);
    // D: sliding-window blend, 8192 waves x 1024 float4s
    k_stack<<<2048, 256, 0, stream>>>(stack, ws, out + OUTN + HID);
}